// Round 5
// baseline (745.039 us; speedup 1.0000x reference)
//
#include <hip/hip_runtime.h>
#include <hip/hip_bf16.h>

#define N_V 100000
#define N_E 20000
#define N_P 1600000
#define FDIM 128
#define HDIM 128
#define BN_EPS 1e-5f

// ---- bucket/sort geometry ----
#define SORT_C 4096                // pairs per sort block
#define SORT_BLOCKS ((N_P + SORT_C - 1) / SORT_C)   // 391
#define NB_E 313                   // edge buckets (64 edges each)
#define EB_SHIFT 6
#define EB_REGION 9216             // slots per edge bucket (mean ~8050, +6 sigma)
#define EB_SORT 5888               // max valid entries per bucket (mean 5112)
#define NB_V 391                   // vertex buckets (256 vertices each)
#define VB_SHIFT 8
#define VB_REGION 8192             // slots per vertex bucket (mean ~7040)
#define VB_SORT 4608               // max valid entries per bucket (mean 4096)
#define SENTINEL 0xFFFFFFFFu

__device__ __forceinline__ float bf_lo(unsigned u) {
    return __uint_as_float(u << 16);
}
__device__ __forceinline__ float bf_hi(unsigned u) {
    return __uint_as_float(u & 0xffff0000u);
}

// ---------------------------------------------------------------------------
// Kernel A: h = X @ W + b  -> bf16x2-packed h  (32 rows/block)
// ---------------------------------------------------------------------------
__global__ __launch_bounds__(256) void k_gemm_bias(
    const float* __restrict__ X, const float* __restrict__ W,
    const float* __restrict__ b, unsigned* __restrict__ h_u) {
    __shared__ float Ws[FDIM * HDIM];   // 64 KB
    __shared__ float Xs[32 * FDIM];     // 16 KB
    const int t = threadIdx.x;
    const int row0 = blockIdx.x * 32;

    const float4* W4 = (const float4*)W;
    float4* Ws4 = (float4*)Ws;
    #pragma unroll
    for (int i = 0; i < (FDIM * HDIM / 4) / 256; ++i)
        Ws4[t + i * 256] = W4[t + i * 256];
    const float4* X4 = (const float4*)(X + (size_t)row0 * FDIM);
    float4* Xs4 = (float4*)Xs;
    #pragma unroll
    for (int i = 0; i < (32 * FDIM / 4) / 256; ++i)
        Xs4[t + i * 256] = X4[t + i * 256];
    __syncthreads();

    const int r  = t >> 3;          // 0..31 local row
    const int cg = (t & 7) * 16;    // channel group start

    float acc[16];
    #pragma unroll
    for (int c = 0; c < 16; ++c) acc[c] = b[cg + c];

    const float* xrow = Xs + r * FDIM;
    for (int k = 0; k < FDIM; k += 4) {
        float4 xv = *(const float4*)(xrow + k);
        const float xs[4] = {xv.x, xv.y, xv.z, xv.w};
        #pragma unroll
        for (int j = 0; j < 4; ++j) {
            const float x = xs[j];
            const float* wrow = Ws + (k + j) * HDIM + cg;
            #pragma unroll
            for (int c = 0; c < 16; ++c) acc[c] += x * wrow[c];
        }
    }
    unsigned packed[8];
    #pragma unroll
    for (int j = 0; j < 8; ++j) {
        __hip_bfloat162 p;
        p.x = __float2bfloat16(acc[2 * j]);
        p.y = __float2bfloat16(acc[2 * j + 1]);
        packed[j] = *(unsigned*)&p;
    }
    unsigned* hrow = h_u + (size_t)(row0 + r) * 64 + (t & 7) * 8;
    ((uint4*)hrow)[0] = make_uint4(packed[0], packed[1], packed[2], packed[3]);
    ((uint4*)hrow)[1] = make_uint4(packed[4], packed[5], packed[6], packed[7]);
}

// ---------------------------------------------------------------------------
// Kernel B: per-channel sum & sumsq of bf16 h
// ---------------------------------------------------------------------------
#define BN_BLOCKS 512
#define BN_ROWS_PER_BLOCK 196
__global__ __launch_bounds__(256) void k_bn_stats(
    const unsigned* __restrict__ h_u, float* __restrict__ sums /* [256] */) {
    const int t = threadIdx.x;
    const int c = t & 127, half = t >> 7;
    const int r0 = blockIdx.x * BN_ROWS_PER_BLOCK;
    const int r1 = min(r0 + BN_ROWS_PER_BLOCK, N_V);
    float s = 0.f, ss = 0.f;
    for (int r = r0 + half; r < r1; r += 2) {
        unsigned u = h_u[(size_t)r * 64 + (c >> 1)];
        float x = (c & 1) ? bf_hi(u) : bf_lo(u);
        s += x;
        ss += x * x;
    }
    __shared__ float ls[256], lss[256];
    ls[t] = s; lss[t] = ss;
    __syncthreads();
    if (t < 128) {
        atomicAdd(&sums[c],       ls[t] + ls[t + 128]);
        atomicAdd(&sums[128 + c], lss[t] + lss[t + 128]);
    }
}

// ---------------------------------------------------------------------------
// Kernel C: finalize BN -> scale/shift
// ---------------------------------------------------------------------------
__global__ void k_bn_final(const float* __restrict__ sums,
                           const float* __restrict__ gamma,
                           const float* __restrict__ beta,
                           float* __restrict__ scale, float* __restrict__ shift) {
    const int c = threadIdx.x;
    const float inv_n = 1.0f / (float)N_V;
    const float mu  = sums[c] * inv_n;
    const float var = sums[128 + c] * inv_n - mu * mu;
    const float inv = rsqrtf(var + BN_EPS);
    const float sc  = gamma[c] * inv;
    scale[c] = sc;
    shift[c] = beta[c] - mu * sc;
}

// ---------------------------------------------------------------------------
// Kernel D: LDS-staged chunk sort with line-aligned full-line flush.
// Each block sorts SORT_C pairs by coarse bucket in LDS, then flushes each
// bucket run to its global region with ONE atomic (rounded to 16-entry lines;
// tail slots = SENTINEL).  No per-pair global atomics, no partial-line writes.
// ---------------------------------------------------------------------------
template <int NB, int SHIFT, int PACK_SHIFT, int REGION>
__global__ __launch_bounds__(256) void k_sort(
    const int* __restrict__ key, const int* __restrict__ other,
    int* __restrict__ gcnt, unsigned* __restrict__ part) {
    __shared__ unsigned stage[SORT_C];           // 16 KB
    __shared__ int hist[NB];
    __shared__ int offs[NB + 1];
    __shared__ int cur[NB];
    __shared__ int gbase[NB];
    __shared__ int partial[256];
    const int t = threadIdx.x;
    const int p0 = blockIdx.x * SORT_C;
    const int n = min(SORT_C, N_P - p0);

    for (int k = t; k < NB; k += 256) hist[k] = 0;
    __syncthreads();
    // pass 1: histogram
    for (int i = t; i < n; i += 256)
        atomicAdd(&hist[((unsigned)key[p0 + i]) >> SHIFT], 1);
    __syncthreads();
    // exclusive scan hist -> offs (blocked + Hillis-Steele over 256 partials)
    constexpr int G = (NB + 255) / 256;
    int loc[G];
    int s = 0;
    #pragma unroll
    for (int g = 0; g < G; ++g) {
        int idx = t * G + g;
        loc[g] = s;
        if (idx < NB) s += hist[idx];
    }
    partial[t] = s;
    __syncthreads();
    for (int d = 1; d < 256; d <<= 1) {
        int v = (t >= d) ? partial[t - d] : 0;
        __syncthreads();
        partial[t] += v;
        __syncthreads();
    }
    const int base = (t > 0) ? partial[t - 1] : 0;
    #pragma unroll
    for (int g = 0; g < G; ++g) {
        int idx = t * G + g;
        if (idx < NB) { offs[idx] = base + loc[g]; cur[idx] = base + loc[g]; }
    }
    if (t == 255) offs[NB] = partial[255];
    __syncthreads();
    // pass 2: place into LDS stage, bucket-sorted
    for (int i = t; i < n; i += 256) {
        const int kv = key[p0 + i];
        const int kk = ((unsigned)kv) >> SHIFT;
        const unsigned pk = ((unsigned)(kv & ((1 << SHIFT) - 1)) << PACK_SHIFT) |
                            (unsigned)other[p0 + i];
        const int pos = atomicAdd(&cur[kk], 1);
        stage[pos] = pk;
    }
    __syncthreads();
    // allocate line-aligned global space: one atomic per (block,bucket)
    for (int k = t; k < NB; k += 256) {
        const int c = hist[k];
        gbase[k] = (c > 0) ? atomicAdd(&gcnt[k], (c + 15) & ~15) : 0;
    }
    __syncthreads();
    // flush: 8 threads per bucket, whole lines (tail = SENTINEL)
    for (int k = t >> 3; k < NB; k += 32) {
        const int c = hist[k];
        if (c == 0) continue;
        int cpad = (c + 15) & ~15;
        const int gb = gbase[k];
        if (gb >= REGION) continue;                 // statistical impossibility guard
        cpad = min(cpad, REGION - gb);
        unsigned* dst = part + (size_t)k * REGION + gb;
        const int lo = offs[k];
        for (int j = t & 7; j < cpad; j += 8)
            dst[j] = (j < c) ? stage[lo + j] : SENTINEL;
    }
}

// ---------------------------------------------------------------------------
// Kernel E: per-edge-bucket LDS counting sort + fused gather-reduce.
// One block per 64 edges; reads its region twice (hist, then scatter).
// ---------------------------------------------------------------------------
__global__ __launch_bounds__(256) void k_edge_bucket(
    const unsigned* __restrict__ h_u, const unsigned* __restrict__ partE,
    const int* __restrict__ gcntE, const float* __restrict__ scale,
    const float* __restrict__ shift, unsigned* __restrict__ xe_u) {
    __shared__ unsigned B[EB_SORT];   // 23.5 KB
    __shared__ int hist[64], offs[65], cur[64];
    const int bkt = blockIdx.x;
    const int t = threadIdx.x;
    const int tot = min(gcntE[bkt], EB_REGION);
    const unsigned* src = partE + (size_t)bkt * EB_REGION;

    if (t < 64) hist[t] = 0;
    __syncthreads();
    for (int i = t; i < tot; i += 256) {
        unsigned a = src[i];
        if (a != SENTINEL) atomicAdd(&hist[a >> 17], 1);
    }
    __syncthreads();
    if (t == 0) {
        offs[0] = 0;
        for (int k = 0; k < 64; ++k) offs[k + 1] = offs[k] + hist[k];
    }
    if (t < 64) cur[t] = 0;
    __syncthreads();
    for (int i = t; i < tot; i += 256) {
        unsigned a = src[i];
        if (a == SENTINEL) continue;
        const int k = a >> 17;
        const int pos = offs[k] + atomicAdd(&cur[k], 1);
        if (pos < EB_SORT) B[pos] = a & 0x1FFFFu;
    }
    __syncthreads();
    // fused gather-reduce: 4 waves x 16 edges
    const int wave = t >> 6, lane = t & 63;
    const float2 sc = ((const float2*)scale)[lane];
    const float2 sh = ((const float2*)shift)[lane];
    for (int el = wave; el < 64; el += 4) {
        const int e = bkt * 64 + el;
        if (e >= N_E) break;
        const int beg = offs[el], end = offs[el + 1];
        const int cnt = end - beg;
        float s0 = 0.f, s1 = 0.f;
        int j = beg;
        for (; j + 1 < end; j += 2) {
            unsigned u0 = h_u[(size_t)B[j] * 64 + lane];
            unsigned u1 = h_u[(size_t)B[j + 1] * 64 + lane];
            s0 += bf_lo(u0) + bf_lo(u1);
            s1 += bf_hi(u0) + bf_hi(u1);
        }
        if (j < end) {
            unsigned u0 = h_u[(size_t)B[j] * 64 + lane];
            s0 += bf_lo(u0);
            s1 += bf_hi(u0);
        }
        float m0 = 0.f, m1 = 0.f;
        if (cnt > 0) {
            const float rc = 1.0f / (float)cnt;
            m0 = sc.x * s0 * rc + sh.x;
            m1 = sc.y * s1 * rc + sh.y;
        }
        __hip_bfloat162 pk;
        pk.x = __float2bfloat16(m0);
        pk.y = __float2bfloat16(m1);
        xe_u[(size_t)e * 64 + lane] = *(unsigned*)&pk;
    }
}

// ---------------------------------------------------------------------------
// Kernel F: per-vertex-bucket LDS counting sort + fused gather-reduce + ReLU.
// One block per 256 vertices.
// ---------------------------------------------------------------------------
__global__ __launch_bounds__(256) void k_vert_bucket(
    const unsigned* __restrict__ xe_u, const unsigned* __restrict__ partV,
    const int* __restrict__ gcntV, float* __restrict__ out) {
    __shared__ unsigned B[VB_SORT];   // 18.4 KB
    __shared__ int hist[256], offs[257], cur[256], partial[256];
    const int bkt = blockIdx.x;
    const int t = threadIdx.x;
    const int tot = min(gcntV[bkt], VB_REGION);
    const unsigned* src = partV + (size_t)bkt * VB_REGION;

    hist[t] = 0;
    __syncthreads();
    for (int i = t; i < tot; i += 256) {
        unsigned a = src[i];
        if (a != SENTINEL) atomicAdd(&hist[a >> 15], 1);
    }
    __syncthreads();
    // parallel exclusive scan of hist[256]
    partial[t] = hist[t];
    __syncthreads();
    for (int d = 1; d < 256; d <<= 1) {
        int v = (t >= d) ? partial[t - d] : 0;
        __syncthreads();
        partial[t] += v;
        __syncthreads();
    }
    offs[t] = partial[t] - hist[t];
    if (t == 255) offs[256] = partial[255];
    cur[t] = 0;
    __syncthreads();
    for (int i = t; i < tot; i += 256) {
        unsigned a = src[i];
        if (a == SENTINEL) continue;
        const int k = a >> 15;
        const int pos = offs[k] + atomicAdd(&cur[k], 1);
        if (pos < VB_SORT) B[pos] = a & 0x7FFFu;
    }
    __syncthreads();
    const int wave = t >> 6, lane = t & 63;
    float2* out2 = (float2*)out;
    for (int vl = wave; vl < 256; vl += 4) {
        const int v = bkt * 256 + vl;
        if (v >= N_V) break;
        const int beg = offs[vl], end = offs[vl + 1];
        const int cnt = end - beg;
        float s0 = 0.f, s1 = 0.f;
        int j = beg;
        for (; j + 1 < end; j += 2) {
            unsigned u0 = xe_u[(size_t)B[j] * 64 + lane];
            unsigned u1 = xe_u[(size_t)B[j + 1] * 64 + lane];
            s0 += bf_lo(u0) + bf_lo(u1);
            s1 += bf_hi(u0) + bf_hi(u1);
        }
        if (j < end) {
            unsigned u0 = xe_u[(size_t)B[j] * 64 + lane];
            s0 += bf_lo(u0);
            s1 += bf_hi(u0);
        }
        const float rc = 1.0f / (float)max(cnt, 1);
        out2[(size_t)v * 64 + lane] =
            make_float2(fmaxf(s0 * rc, 0.f), fmaxf(s1 * rc, 0.f));
    }
}

// ---------------------------------------------------------------------------
extern "C" void kernel_launch(void* const* d_in, const int* in_sizes, int n_in,
                              void* d_out, int out_size, void* d_ws, size_t ws_size,
                              hipStream_t stream) {
    const float* X     = (const float*)d_in[0];
    const int*   vid   = (const int*)d_in[1];
    const int*   eid   = (const int*)d_in[2];
    const float* W     = (const float*)d_in[3];
    const float* b     = (const float*)d_in[4];
    const float* gamma = (const float*)d_in[5];
    const float* beta  = (const float*)d_in[6];
    float* out = (float*)d_out;

    // workspace layout
    char* ws = (char*)d_ws;
    unsigned* h_u   = (unsigned*)ws;  ws += (size_t)N_V * 64 * 4;            // 25.6 MB
    unsigned* xe_u  = (unsigned*)ws;  ws += (size_t)N_E * 64 * 4;            //  5.1 MB
    unsigned* partE = (unsigned*)ws;  ws += (size_t)NB_E * EB_REGION * 4;    // 11.5 MB
    unsigned* partV = (unsigned*)ws;  ws += (size_t)NB_V * VB_REGION * 4;    // 12.8 MB
    // --- zeroed region ---
    char* zbase = ws;
    int*   gcntE = (int*)ws;          ws += (size_t)NB_E * 4;
    int*   gcntV = (int*)ws;          ws += (size_t)NB_V * 4;
    float* sums  = (float*)ws;        ws += 256 * 4;
    // --- end zeroed region ---
    float* scale = (float*)ws;        ws += 128 * 4;
    float* shift = (float*)ws;        ws += 128 * 4;

    hipMemsetAsync(zbase, 0, (size_t)((char*)scale - zbase), stream);

    k_gemm_bias<<<N_V / 32, 256, 0, stream>>>(X, W, b, h_u);
    k_bn_stats<<<BN_BLOCKS, 256, 0, stream>>>(h_u, sums);
    k_bn_final<<<1, 128, 0, stream>>>(sums, gamma, beta, scale, shift);

    k_sort<NB_E, EB_SHIFT, 17, EB_REGION>
        <<<SORT_BLOCKS, 256, 0, stream>>>(eid, vid, gcntE, partE);
    k_sort<NB_V, VB_SHIFT, 15, VB_REGION>
        <<<SORT_BLOCKS, 256, 0, stream>>>(vid, eid, gcntV, partV);

    k_edge_bucket<<<NB_E, 256, 0, stream>>>(h_u, partE, gcntE, scale, shift, xe_u);
    k_vert_bucket<<<NB_V, 256, 0, stream>>>(xe_u, partV, gcntV, out);
}

// Round 6
// 461.351 us; speedup vs baseline: 1.6149x; 1.6149x over previous
//
#include <hip/hip_runtime.h>
#include <hip/hip_bf16.h>

#define N_V 100000
#define N_E 20000
#define N_P 1600000
#define FDIM 128
#define HDIM 128
#define BN_EPS 1e-5f

// ---- bucket/sort geometry ----
#define SORT_C 4096
#define SORT_BLOCKS ((N_P + SORT_C - 1) / SORT_C)   // 391
#define NB_E 313                   // edge buckets (64 edges each)
#define EB_SHIFT 6
#define EB_REGION 9216             // slots per edge bucket region
#define EB_SORT 5888               // max valid entries per bucket (mean 5112)
#define NB_V 391                   // vertex buckets (256 vertices each)
#define VB_SHIFT 8
#define VB_REGION 8192
#define VB_SORT 4608               // max valid entries per bucket (mean 4096)
#define SENTINEL 0xFFFFFFFFu

__device__ __forceinline__ float bf_lo(unsigned u) {
    return __uint_as_float(u << 16);
}
__device__ __forceinline__ float bf_hi(unsigned u) {
    return __uint_as_float(u & 0xffff0000u);
}

// ---------------------------------------------------------------------------
// Kernel A: h = X @ W + b  -> bf16x2-packed h  (32 rows/block)
// ---------------------------------------------------------------------------
__global__ __launch_bounds__(256) void k_gemm_bias(
    const float* __restrict__ X, const float* __restrict__ W,
    const float* __restrict__ b, unsigned* __restrict__ h_u) {
    __shared__ float Ws[FDIM * HDIM];   // 64 KB
    __shared__ float Xs[32 * FDIM];     // 16 KB
    const int t = threadIdx.x;
    const int row0 = blockIdx.x * 32;

    const float4* W4 = (const float4*)W;
    float4* Ws4 = (float4*)Ws;
    #pragma unroll
    for (int i = 0; i < (FDIM * HDIM / 4) / 256; ++i)
        Ws4[t + i * 256] = W4[t + i * 256];
    const float4* X4 = (const float4*)(X + (size_t)row0 * FDIM);
    float4* Xs4 = (float4*)Xs;
    #pragma unroll
    for (int i = 0; i < (32 * FDIM / 4) / 256; ++i)
        Xs4[t + i * 256] = X4[t + i * 256];
    __syncthreads();

    const int r  = t >> 3;          // 0..31 local row
    const int cg = (t & 7) * 16;    // channel group start

    float acc[16];
    #pragma unroll
    for (int c = 0; c < 16; ++c) acc[c] = b[cg + c];

    const float* xrow = Xs + r * FDIM;
    for (int k = 0; k < FDIM; k += 4) {
        float4 xv = *(const float4*)(xrow + k);
        const float xs[4] = {xv.x, xv.y, xv.z, xv.w};
        #pragma unroll
        for (int j = 0; j < 4; ++j) {
            const float x = xs[j];
            const float* wrow = Ws + (k + j) * HDIM + cg;
            #pragma unroll
            for (int c = 0; c < 16; ++c) acc[c] += x * wrow[c];
        }
    }
    unsigned packed[8];
    #pragma unroll
    for (int j = 0; j < 8; ++j) {
        __hip_bfloat162 p;
        p.x = __float2bfloat16(acc[2 * j]);
        p.y = __float2bfloat16(acc[2 * j + 1]);
        packed[j] = *(unsigned*)&p;
    }
    unsigned* hrow = h_u + (size_t)(row0 + r) * 64 + (t & 7) * 8;
    ((uint4*)hrow)[0] = make_uint4(packed[0], packed[1], packed[2], packed[3]);
    ((uint4*)hrow)[1] = make_uint4(packed[4], packed[5], packed[6], packed[7]);
}

// ---------------------------------------------------------------------------
// Kernel B: per-channel sum & sumsq of bf16 h
// ---------------------------------------------------------------------------
#define BN_BLOCKS 512
#define BN_ROWS_PER_BLOCK 196
__global__ __launch_bounds__(256) void k_bn_stats(
    const unsigned* __restrict__ h_u, float* __restrict__ sums /* [256] */) {
    const int t = threadIdx.x;
    const int c = t & 127, half = t >> 7;
    const int r0 = blockIdx.x * BN_ROWS_PER_BLOCK;
    const int r1 = min(r0 + BN_ROWS_PER_BLOCK, N_V);
    float s = 0.f, ss = 0.f;
    for (int r = r0 + half; r < r1; r += 2) {
        unsigned u = h_u[(size_t)r * 64 + (c >> 1)];
        float x = (c & 1) ? bf_hi(u) : bf_lo(u);
        s += x;
        ss += x * x;
    }
    __shared__ float ls[256], lss[256];
    ls[t] = s; lss[t] = ss;
    __syncthreads();
    if (t < 128) {
        atomicAdd(&sums[c],       ls[t] + ls[t + 128]);
        atomicAdd(&sums[128 + c], lss[t] + lss[t + 128]);
    }
}

// ---------------------------------------------------------------------------
// Kernel C: finalize BN -> scale/shift
// ---------------------------------------------------------------------------
__global__ void k_bn_final(const float* __restrict__ sums,
                           const float* __restrict__ gamma,
                           const float* __restrict__ beta,
                           float* __restrict__ scale, float* __restrict__ shift) {
    const int c = threadIdx.x;
    const float inv_n = 1.0f / (float)N_V;
    const float mu  = sums[c] * inv_n;
    const float var = sums[128 + c] * inv_n - mu * mu;
    const float inv = rsqrtf(var + BN_EPS);
    const float sc  = gamma[c] * inv;
    scale[c] = sc;
    shift[c] = beta[c] - mu * sc;
}

// ---------------------------------------------------------------------------
// Kernel D: LDS-staged chunk sort with line-aligned full-line flush.
// (unchanged from R5 — proven: WRITE_SIZE ~1x payload, cheap)
// ---------------------------------------------------------------------------
template <int NB, int SHIFT, int PACK_SHIFT, int REGION>
__global__ __launch_bounds__(256) void k_sort(
    const int* __restrict__ key, const int* __restrict__ other,
    int* __restrict__ gcnt, unsigned* __restrict__ part) {
    __shared__ unsigned stage[SORT_C];           // 16 KB
    __shared__ int hist[NB];
    __shared__ int offs[NB + 1];
    __shared__ int cur[NB];
    __shared__ int gbase[NB];
    __shared__ int partial[256];
    const int t = threadIdx.x;
    const int p0 = blockIdx.x * SORT_C;
    const int n = min(SORT_C, N_P - p0);

    for (int k = t; k < NB; k += 256) hist[k] = 0;
    __syncthreads();
    for (int i = t; i < n; i += 256)
        atomicAdd(&hist[((unsigned)key[p0 + i]) >> SHIFT], 1);
    __syncthreads();
    constexpr int G = (NB + 255) / 256;
    int loc[G];
    int s = 0;
    #pragma unroll
    for (int g = 0; g < G; ++g) {
        int idx = t * G + g;
        loc[g] = s;
        if (idx < NB) s += hist[idx];
    }
    partial[t] = s;
    __syncthreads();
    for (int d = 1; d < 256; d <<= 1) {
        int v = (t >= d) ? partial[t - d] : 0;
        __syncthreads();
        partial[t] += v;
        __syncthreads();
    }
    const int base = (t > 0) ? partial[t - 1] : 0;
    #pragma unroll
    for (int g = 0; g < G; ++g) {
        int idx = t * G + g;
        if (idx < NB) { offs[idx] = base + loc[g]; cur[idx] = base + loc[g]; }
    }
    if (t == 255) offs[NB] = partial[255];
    __syncthreads();
    for (int i = t; i < n; i += 256) {
        const int kv = key[p0 + i];
        const int kk = ((unsigned)kv) >> SHIFT;
        const unsigned pk = ((unsigned)(kv & ((1 << SHIFT) - 1)) << PACK_SHIFT) |
                            (unsigned)other[p0 + i];
        const int pos = atomicAdd(&cur[kk], 1);
        stage[pos] = pk;
    }
    __syncthreads();
    for (int k = t; k < NB; k += 256) {
        const int c = hist[k];
        gbase[k] = (c > 0) ? atomicAdd(&gcnt[k], (c + 15) & ~15) : 0;
    }
    __syncthreads();
    for (int k = t >> 3; k < NB; k += 32) {
        const int c = hist[k];
        if (c == 0) continue;
        int cpad = (c + 15) & ~15;
        const int gb = gbase[k];
        if (gb >= REGION) continue;
        cpad = min(cpad, REGION - gb);
        unsigned* dst = part + (size_t)k * REGION + gb;
        const int lo = offs[k];
        for (int j = t & 7; j < cpad; j += 8)
            dst[j] = (j < c) ? stage[lo + j] : SENTINEL;
    }
}

// ---------------------------------------------------------------------------
// Kernel E: bucket region -> compact sorted CSR (adjacency + seg off/cnt).
// Wave-aggregated sentinel-skipping compaction, LDS counting sort, coalesced
// compact writeback.  One block per bucket.
// ---------------------------------------------------------------------------
template <int NKEY, int PACK_SHIFT, int CAP, int REGION, int STRIDE>
__global__ __launch_bounds__(256) void k_csr(
    const unsigned* __restrict__ part, const int* __restrict__ gcnt,
    int nkeys_total, int* __restrict__ segoff, int* __restrict__ segcnt,
    unsigned* __restrict__ csr) {
    __shared__ unsigned A[CAP];
    __shared__ unsigned B[CAP];
    __shared__ int hist[NKEY], offs[NKEY + 1], cur[NKEY];
    __shared__ int lcur;
    const int bkt = blockIdx.x;
    const int t = threadIdx.x;
    const int lane = t & 63;
    const unsigned mask = (1u << PACK_SHIFT) - 1u;
    const int tot = min(gcnt[bkt], REGION);
    const unsigned* src = part + (size_t)bkt * REGION;

    if (t == 0) lcur = 0;
    for (int k = t; k < NKEY; k += 256) hist[k] = 0;
    __syncthreads();
    // wave-aggregated compaction of valid entries into A
    for (int i = t; i < ((tot + 255) & ~255); i += 256) {
        unsigned a = (i < tot) ? src[i] : SENTINEL;
        const bool valid = (a != SENTINEL);
        const unsigned long long bal = __ballot(valid);
        int wbase = 0;
        if (lane == 0) wbase = atomicAdd(&lcur, __popcll(bal));
        wbase = __shfl(wbase, 0);
        if (valid) {
            const int pos = wbase +
                __popcll(bal & ((1ull << lane) - 1ull));
            if (pos < CAP) A[pos] = a;
        }
    }
    __syncthreads();
    const int total = min(lcur, CAP);
    for (int i = t; i < total; i += 256)
        atomicAdd(&hist[A[i] >> PACK_SHIFT], 1);
    __syncthreads();
    if (t == 0) {
        int acc = 0;
        for (int k = 0; k < NKEY; ++k) { offs[k] = acc; acc += hist[k]; }
        offs[NKEY] = acc;
    }
    for (int k = t; k < NKEY; k += 256) cur[k] = 0;
    __syncthreads();
    for (int i = t; i < total; i += 256) {
        const unsigned a = A[i];
        const int k = a >> PACK_SHIFT;
        const int pos = offs[k] + atomicAdd(&cur[k], 1);
        B[pos] = a & mask;
    }
    __syncthreads();
    unsigned* dst = csr + (size_t)bkt * STRIDE;
    for (int i = t; i < total; i += 256) dst[i] = B[i];
    for (int k = t; k < NKEY; k += 256) {
        const int g = bkt * NKEY + k;
        if (g < nkeys_total) {
            segoff[g] = bkt * STRIDE + offs[k];
            segcnt[g] = hist[k];
        }
    }
}

// ---------------------------------------------------------------------------
// Kernel F: per-edge gather-reduce.  One wave per edge, no LDS, 4-way MLP.
// Xe = scale*(sum h)/cnt + shift  (bf16x2 out)
// ---------------------------------------------------------------------------
__global__ __launch_bounds__(256) void k_edge_gather(
    const unsigned* __restrict__ h_u, const unsigned* __restrict__ csrE,
    const int* __restrict__ eoff, const int* __restrict__ ecnt,
    const float* __restrict__ scale, const float* __restrict__ shift,
    unsigned* __restrict__ xe_u) {
    const int e = blockIdx.x * 4 + (threadIdx.x >> 6);
    if (e >= N_E) return;
    const int l = threadIdx.x & 63;
    const int o = eoff[e], n = ecnt[e];
    const float2 sc = ((const float2*)scale)[l];
    const float2 sh = ((const float2*)shift)[l];
    float s0 = 0.f, s1 = 0.f, s2 = 0.f, s3 = 0.f;
    int j = 0;
    for (; j + 3 < n; j += 4) {
        const int v0 = csrE[o + j],     v1 = csrE[o + j + 1];
        const int v2 = csrE[o + j + 2], v3 = csrE[o + j + 3];
        const unsigned u0 = h_u[(size_t)v0 * 64 + l];
        const unsigned u1 = h_u[(size_t)v1 * 64 + l];
        const unsigned u2 = h_u[(size_t)v2 * 64 + l];
        const unsigned u3 = h_u[(size_t)v3 * 64 + l];
        s0 += bf_lo(u0) + bf_lo(u1);
        s1 += bf_hi(u0) + bf_hi(u1);
        s2 += bf_lo(u2) + bf_lo(u3);
        s3 += bf_hi(u2) + bf_hi(u3);
    }
    for (; j < n; ++j) {
        const unsigned u0 = h_u[(size_t)csrE[o + j] * 64 + l];
        s0 += bf_lo(u0);
        s1 += bf_hi(u0);
    }
    s0 += s2; s1 += s3;
    float m0 = 0.f, m1 = 0.f;
    if (n > 0) {
        const float rc = 1.0f / (float)n;
        m0 = sc.x * s0 * rc + sh.x;
        m1 = sc.y * s1 * rc + sh.y;
    }
    __hip_bfloat162 pk;
    pk.x = __float2bfloat16(m0);
    pk.y = __float2bfloat16(m1);
    xe_u[(size_t)e * 64 + l] = *(unsigned*)&pk;
}

// ---------------------------------------------------------------------------
// Kernel G: per-vertex gather-reduce + ReLU.  One wave per vertex, no LDS.
// ---------------------------------------------------------------------------
__global__ __launch_bounds__(256) void k_vert_gather(
    const unsigned* __restrict__ xe_u, const unsigned* __restrict__ csrV,
    const int* __restrict__ voff, const int* __restrict__ vcnt,
    float* __restrict__ out) {
    const int v = blockIdx.x * 4 + (threadIdx.x >> 6);
    if (v >= N_V) return;
    const int l = threadIdx.x & 63;
    const int o = voff[v], n = vcnt[v];
    float s0 = 0.f, s1 = 0.f, s2 = 0.f, s3 = 0.f;
    int j = 0;
    for (; j + 3 < n; j += 4) {
        const int e0 = csrV[o + j],     e1 = csrV[o + j + 1];
        const int e2 = csrV[o + j + 2], e3 = csrV[o + j + 3];
        const unsigned u0 = xe_u[(size_t)e0 * 64 + l];
        const unsigned u1 = xe_u[(size_t)e1 * 64 + l];
        const unsigned u2 = xe_u[(size_t)e2 * 64 + l];
        const unsigned u3 = xe_u[(size_t)e3 * 64 + l];
        s0 += bf_lo(u0) + bf_lo(u1);
        s1 += bf_hi(u0) + bf_hi(u1);
        s2 += bf_lo(u2) + bf_lo(u3);
        s3 += bf_hi(u2) + bf_hi(u3);
    }
    for (; j < n; ++j) {
        const unsigned u0 = xe_u[(size_t)csrV[o + j] * 64 + l];
        s0 += bf_lo(u0);
        s1 += bf_hi(u0);
    }
    s0 += s2; s1 += s3;
    const float rc = 1.0f / (float)max(n, 1);
    ((float2*)out)[(size_t)v * 64 + l] =
        make_float2(fmaxf(s0 * rc, 0.f), fmaxf(s1 * rc, 0.f));
}

// ---------------------------------------------------------------------------
extern "C" void kernel_launch(void* const* d_in, const int* in_sizes, int n_in,
                              void* d_out, int out_size, void* d_ws, size_t ws_size,
                              hipStream_t stream) {
    const float* X     = (const float*)d_in[0];
    const int*   vid   = (const int*)d_in[1];
    const int*   eid   = (const int*)d_in[2];
    const float* W     = (const float*)d_in[3];
    const float* b     = (const float*)d_in[4];
    const float* gamma = (const float*)d_in[5];
    const float* beta  = (const float*)d_in[6];
    float* out = (float*)d_out;

    // workspace layout
    char* ws = (char*)d_ws;
    unsigned* h_u   = (unsigned*)ws;  ws += (size_t)N_V * 64 * 4;            // 25.6 MB
    unsigned* xe_u  = (unsigned*)ws;  ws += (size_t)N_E * 64 * 4;            //  5.1 MB
    unsigned* partE = (unsigned*)ws;  ws += (size_t)NB_E * EB_REGION * 4;    // 11.5 MB
    unsigned* partV = (unsigned*)ws;  ws += (size_t)NB_V * VB_REGION * 4;    // 12.8 MB
    unsigned* csrE  = (unsigned*)ws;  ws += (size_t)NB_E * EB_SORT * 4;      //  7.4 MB
    unsigned* csrV  = (unsigned*)ws;  ws += (size_t)NB_V * VB_SORT * 4;      //  7.2 MB
    int* eoff = (int*)ws;             ws += (size_t)N_E * 4;
    int* ecnt = (int*)ws;             ws += (size_t)N_E * 4;
    int* voff = (int*)ws;             ws += (size_t)N_V * 4;
    int* vcnt = (int*)ws;             ws += (size_t)N_V * 4;
    // --- zeroed region ---
    char* zbase = ws;
    int*   gcntE = (int*)ws;          ws += (size_t)NB_E * 4;
    int*   gcntV = (int*)ws;          ws += (size_t)NB_V * 4;
    float* sums  = (float*)ws;        ws += 256 * 4;
    // --- end zeroed region ---
    float* scale = (float*)ws;        ws += 128 * 4;
    float* shift = (float*)ws;        ws += 128 * 4;

    hipMemsetAsync(zbase, 0, (size_t)((char*)scale - zbase), stream);

    k_gemm_bias<<<N_V / 32, 256, 0, stream>>>(X, W, b, h_u);
    k_bn_stats<<<BN_BLOCKS, 256, 0, stream>>>(h_u, sums);
    k_bn_final<<<1, 128, 0, stream>>>(sums, gamma, beta, scale, shift);

    k_sort<NB_E, EB_SHIFT, 17, EB_REGION>
        <<<SORT_BLOCKS, 256, 0, stream>>>(eid, vid, gcntE, partE);
    k_sort<NB_V, VB_SHIFT, 15, VB_REGION>
        <<<SORT_BLOCKS, 256, 0, stream>>>(vid, eid, gcntV, partV);

    k_csr<64, 17, EB_SORT, EB_REGION, EB_SORT>
        <<<NB_E, 256, 0, stream>>>(partE, gcntE, N_E, eoff, ecnt, csrE);
    k_csr<256, 15, VB_SORT, VB_REGION, VB_SORT>
        <<<NB_V, 256, 0, stream>>>(partV, gcntV, N_V, voff, vcnt, csrV);

    k_edge_gather<<<(N_E + 3) / 4, 256, 0, stream>>>(h_u, csrE, eoff, ecnt,
                                                     scale, shift, xe_u);
    k_vert_gather<<<(N_V + 3) / 4, 256, 0, stream>>>(xe_u, csrV, voff, vcnt, out);
}

// Round 7
// 376.333 us; speedup vs baseline: 1.9797x; 1.2259x over previous
//
#include <hip/hip_runtime.h>
#include <hip/hip_bf16.h>

#define N_V 100000
#define N_E 20000
#define N_P 1600000
#define FDIM 128
#define HDIM 128
#define BN_EPS 1e-5f

// ---- bucket/sort geometry ----
#define SORT_C 4096
#define SORT_BLOCKS ((N_P + SORT_C - 1) / SORT_C)   // 391
#define NB_E 313                   // edge buckets (64 edges each)
#define EB_SHIFT 6
#define EB_REGION 9216             // slots per edge bucket region
#define EB_SORT 5888               // max valid entries per bucket (mean 5112)
#define NB_V 391                   // vertex buckets (256 vertices each)
#define VB_SHIFT 8
#define VB_REGION 8192
#define VB_SORT 4608               // max valid entries per bucket (mean 4096)
#define SENTINEL 0xFFFFFFFFu

typedef __attribute__((ext_vector_type(8))) short short8;
typedef __attribute__((ext_vector_type(4))) float floatx4;

__device__ __forceinline__ float bf_lo(unsigned u) {
    return __uint_as_float(u << 16);
}
__device__ __forceinline__ float bf_hi(unsigned u) {
    return __uint_as_float(u & 0xffff0000u);
}
// fp32 -> bf16 bits, round-to-nearest-even (values are finite/normal here)
__device__ __forceinline__ unsigned short f2bf(float f) {
    unsigned u = __float_as_uint(f);
    return (unsigned short)((u + 0x7fffu + ((u >> 16) & 1u)) >> 16);
}

// ---------------------------------------------------------------------------
// Kernel A: h = X @ W + b via bf16 MFMA, computed as C^T = W^T · X^T.
// One block = 4 waves; W^T staged in LDS (bf16, +8 pad); each wave computes
// 16-vertex strips (8 channel-tiles of 16), packed bf16x2 stores into h_u.
// ---------------------------------------------------------------------------
#define GEMM_BLOCKS 625
#define WT_STRIDE 136   // 128 + 8 bf16 pad -> 2-way-only LDS conflicts
__global__ __launch_bounds__(256) void k_gemm_mfma(
    const float* __restrict__ X, const float* __restrict__ W,
    const float* __restrict__ bias, unsigned* __restrict__ h_u) {
    __shared__ unsigned short WTs[FDIM * WT_STRIDE];   // ~34 KB
    const int t = threadIdx.x;
    // stage W^T (bf16): coalesced read of W[k][m], transposed write
    for (int idx = t; idx < FDIM * HDIM; idx += 256) {
        const int k = idx >> 7, m = idx & 127;
        WTs[m * WT_STRIDE + k] = f2bf(W[idx]);
    }
    __syncthreads();

    const int wave = t >> 6, lane = t & 63;
    const int quad = lane >> 4, sub = lane & 15;
    const int nstrips = N_V / 16;  // 6250, exact

    for (int s = blockIdx.x * 4 + wave; s < nstrips; s += GEMM_BLOCKS * 4) {
        const int row0 = s * 16;
        // B-fragments: X^T, lane holds X[row0+sub][kt*32 + quad*8 + j]
        short8 xf[4];
        const float* xp = X + (size_t)(row0 + sub) * FDIM + quad * 8;
        #pragma unroll
        for (int kt = 0; kt < 4; ++kt) {
            const float4 a = *(const float4*)(xp + kt * 32);
            const float4 b2 = *(const float4*)(xp + kt * 32 + 4);
            short8 f;
            f[0] = (short)f2bf(a.x);  f[1] = (short)f2bf(a.y);
            f[2] = (short)f2bf(a.z);  f[3] = (short)f2bf(a.w);
            f[4] = (short)f2bf(b2.x); f[5] = (short)f2bf(b2.y);
            f[6] = (short)f2bf(b2.z); f[7] = (short)f2bf(b2.w);
            xf[kt] = f;
        }
        // 8 channel-tiles of 16
        #pragma unroll
        for (int tile = 0; tile < 8; ++tile) {
            floatx4 acc = {0.f, 0.f, 0.f, 0.f};
            const unsigned short* wp =
                WTs + (tile * 16 + sub) * WT_STRIDE + quad * 8;
            #pragma unroll
            for (int kt = 0; kt < 4; ++kt) {
                const short8 af = *(const short8*)(wp + kt * 32);
                acc = __builtin_amdgcn_mfma_f32_16x16x32_bf16(af, xf[kt], acc,
                                                              0, 0, 0);
            }
            const int ch = tile * 16 + quad * 4;   // channels ch..ch+3
            const float4 bb = *(const float4*)(bias + ch);
            const float c0 = acc[0] + bb.x, c1 = acc[1] + bb.y;
            const float c2 = acc[2] + bb.z, c3 = acc[3] + bb.w;
            const unsigned lo = (unsigned)f2bf(c0) | ((unsigned)f2bf(c1) << 16);
            const unsigned hi = (unsigned)f2bf(c2) | ((unsigned)f2bf(c3) << 16);
            uint2* dst = (uint2*)(h_u + (size_t)(row0 + sub) * 64 + (ch >> 1));
            *dst = make_uint2(lo, hi);
        }
    }
}

// ---------------------------------------------------------------------------
// Kernel B: per-channel sum & sumsq of bf16 h
// ---------------------------------------------------------------------------
#define BN_BLOCKS 512
#define BN_ROWS_PER_BLOCK 196
__global__ __launch_bounds__(256) void k_bn_stats(
    const unsigned* __restrict__ h_u, float* __restrict__ sums /* [256] */) {
    const int t = threadIdx.x;
    const int c = t & 127, half = t >> 7;
    const int r0 = blockIdx.x * BN_ROWS_PER_BLOCK;
    const int r1 = min(r0 + BN_ROWS_PER_BLOCK, N_V);
    float s = 0.f, ss = 0.f;
    for (int r = r0 + half; r < r1; r += 2) {
        unsigned u = h_u[(size_t)r * 64 + (c >> 1)];
        float x = (c & 1) ? bf_hi(u) : bf_lo(u);
        s += x;
        ss += x * x;
    }
    __shared__ float ls[256], lss[256];
    ls[t] = s; lss[t] = ss;
    __syncthreads();
    if (t < 128) {
        atomicAdd(&sums[c],       ls[t] + ls[t + 128]);
        atomicAdd(&sums[128 + c], lss[t] + lss[t + 128]);
    }
}

// ---------------------------------------------------------------------------
// Kernel C: finalize BN -> scale/shift
// ---------------------------------------------------------------------------
__global__ void k_bn_final(const float* __restrict__ sums,
                           const float* __restrict__ gamma,
                           const float* __restrict__ beta,
                           float* __restrict__ scale, float* __restrict__ shift) {
    const int c = threadIdx.x;
    const float inv_n = 1.0f / (float)N_V;
    const float mu  = sums[c] * inv_n;
    const float var = sums[128 + c] * inv_n - mu * mu;
    const float inv = rsqrtf(var + BN_EPS);
    const float sc  = gamma[c] * inv;
    scale[c] = sc;
    shift[c] = beta[c] - mu * sc;
}

// ---------------------------------------------------------------------------
// Kernel D: LDS-staged chunk sort with line-aligned full-line flush.
// ---------------------------------------------------------------------------
template <int NB, int SHIFT, int PACK_SHIFT, int REGION>
__global__ __launch_bounds__(256) void k_sort(
    const int* __restrict__ key, const int* __restrict__ other,
    int* __restrict__ gcnt, unsigned* __restrict__ part) {
    __shared__ unsigned stage[SORT_C];           // 16 KB
    __shared__ int hist[NB];
    __shared__ int offs[NB + 1];
    __shared__ int cur[NB];
    __shared__ int gbase[NB];
    __shared__ int partial[256];
    const int t = threadIdx.x;
    const int p0 = blockIdx.x * SORT_C;
    const int n = min(SORT_C, N_P - p0);

    for (int k = t; k < NB; k += 256) hist[k] = 0;
    __syncthreads();
    for (int i = t; i < n; i += 256)
        atomicAdd(&hist[((unsigned)key[p0 + i]) >> SHIFT], 1);
    __syncthreads();
    constexpr int G = (NB + 255) / 256;
    int loc[G];
    int s = 0;
    #pragma unroll
    for (int g = 0; g < G; ++g) {
        int idx = t * G + g;
        loc[g] = s;
        if (idx < NB) s += hist[idx];
    }
    partial[t] = s;
    __syncthreads();
    for (int d = 1; d < 256; d <<= 1) {
        int v = (t >= d) ? partial[t - d] : 0;
        __syncthreads();
        partial[t] += v;
        __syncthreads();
    }
    const int base = (t > 0) ? partial[t - 1] : 0;
    #pragma unroll
    for (int g = 0; g < G; ++g) {
        int idx = t * G + g;
        if (idx < NB) { offs[idx] = base + loc[g]; cur[idx] = base + loc[g]; }
    }
    if (t == 255) offs[NB] = partial[255];
    __syncthreads();
    for (int i = t; i < n; i += 256) {
        const int kv = key[p0 + i];
        const int kk = ((unsigned)kv) >> SHIFT;
        const unsigned pk = ((unsigned)(kv & ((1 << SHIFT) - 1)) << PACK_SHIFT) |
                            (unsigned)other[p0 + i];
        const int pos = atomicAdd(&cur[kk], 1);
        stage[pos] = pk;
    }
    __syncthreads();
    for (int k = t; k < NB; k += 256) {
        const int c = hist[k];
        gbase[k] = (c > 0) ? atomicAdd(&gcnt[k], (c + 15) & ~15) : 0;
    }
    __syncthreads();
    for (int k = t >> 3; k < NB; k += 32) {
        const int c = hist[k];
        if (c == 0) continue;
        int cpad = (c + 15) & ~15;
        const int gb = gbase[k];
        if (gb >= REGION) continue;
        cpad = min(cpad, REGION - gb);
        unsigned* dst = part + (size_t)k * REGION + gb;
        const int lo = offs[k];
        for (int j = t & 7; j < cpad; j += 8)
            dst[j] = (j < c) ? stage[lo + j] : SENTINEL;
    }
}

// ---------------------------------------------------------------------------
// Kernel E: bucket region -> compact sorted CSR (adjacency + seg off/cnt).
// ---------------------------------------------------------------------------
template <int NKEY, int PACK_SHIFT, int CAP, int REGION, int STRIDE>
__global__ __launch_bounds__(256) void k_csr(
    const unsigned* __restrict__ part, const int* __restrict__ gcnt,
    int nkeys_total, int* __restrict__ segoff, int* __restrict__ segcnt,
    unsigned* __restrict__ csr) {
    __shared__ unsigned A[CAP];
    __shared__ unsigned B[CAP];
    __shared__ int hist[NKEY], offs[NKEY + 1], cur[NKEY];
    __shared__ int lcur;
    const int bkt = blockIdx.x;
    const int t = threadIdx.x;
    const int lane = t & 63;
    const unsigned mask = (1u << PACK_SHIFT) - 1u;
    const int tot = min(gcnt[bkt], REGION);
    const unsigned* src = part + (size_t)bkt * REGION;

    if (t == 0) lcur = 0;
    for (int k = t; k < NKEY; k += 256) hist[k] = 0;
    __syncthreads();
    for (int i = t; i < ((tot + 255) & ~255); i += 256) {
        unsigned a = (i < tot) ? src[i] : SENTINEL;
        const bool valid = (a != SENTINEL);
        const unsigned long long bal = __ballot(valid);
        int wbase = 0;
        if (lane == 0) wbase = atomicAdd(&lcur, __popcll(bal));
        wbase = __shfl(wbase, 0);
        if (valid) {
            const int pos = wbase +
                __popcll(bal & ((1ull << lane) - 1ull));
            if (pos < CAP) A[pos] = a;
        }
    }
    __syncthreads();
    const int total = min(lcur, CAP);
    for (int i = t; i < total; i += 256)
        atomicAdd(&hist[A[i] >> PACK_SHIFT], 1);
    __syncthreads();
    if (t == 0) {
        int acc = 0;
        for (int k = 0; k < NKEY; ++k) { offs[k] = acc; acc += hist[k]; }
        offs[NKEY] = acc;
    }
    for (int k = t; k < NKEY; k += 256) cur[k] = 0;
    __syncthreads();
    for (int i = t; i < total; i += 256) {
        const unsigned a = A[i];
        const int k = a >> PACK_SHIFT;
        const int pos = offs[k] + atomicAdd(&cur[k], 1);
        B[pos] = a & mask;
    }
    __syncthreads();
    unsigned* dst = csr + (size_t)bkt * STRIDE;
    for (int i = t; i < total; i += 256) dst[i] = B[i];
    for (int k = t; k < NKEY; k += 256) {
        const int g = bkt * NKEY + k;
        if (g < nkeys_total) {
            segoff[g] = bkt * STRIDE + offs[k];
            segcnt[g] = hist[k];
        }
    }
}

// ---------------------------------------------------------------------------
// Kernel F: per-edge gather-reduce.  One wave per edge, no LDS, 4-way MLP.
// ---------------------------------------------------------------------------
__global__ __launch_bounds__(256) void k_edge_gather(
    const unsigned* __restrict__ h_u, const unsigned* __restrict__ csrE,
    const int* __restrict__ eoff, const int* __restrict__ ecnt,
    const float* __restrict__ scale, const float* __restrict__ shift,
    unsigned* __restrict__ xe_u) {
    const int e = blockIdx.x * 4 + (threadIdx.x >> 6);
    if (e >= N_E) return;
    const int l = threadIdx.x & 63;
    const int o = eoff[e], n = ecnt[e];
    const float2 sc = ((const float2*)scale)[l];
    const float2 sh = ((const float2*)shift)[l];
    float s0 = 0.f, s1 = 0.f, s2 = 0.f, s3 = 0.f;
    int j = 0;
    for (; j + 3 < n; j += 4) {
        const int v0 = csrE[o + j],     v1 = csrE[o + j + 1];
        const int v2 = csrE[o + j + 2], v3 = csrE[o + j + 3];
        const unsigned u0 = h_u[(size_t)v0 * 64 + l];
        const unsigned u1 = h_u[(size_t)v1 * 64 + l];
        const unsigned u2 = h_u[(size_t)v2 * 64 + l];
        const unsigned u3 = h_u[(size_t)v3 * 64 + l];
        s0 += bf_lo(u0) + bf_lo(u1);
        s1 += bf_hi(u0) + bf_hi(u1);
        s2 += bf_lo(u2) + bf_lo(u3);
        s3 += bf_hi(u2) + bf_hi(u3);
    }
    for (; j < n; ++j) {
        const unsigned u0 = h_u[(size_t)csrE[o + j] * 64 + l];
        s0 += bf_lo(u0);
        s1 += bf_hi(u0);
    }
    s0 += s2; s1 += s3;
    float m0 = 0.f, m1 = 0.f;
    if (n > 0) {
        const float rc = 1.0f / (float)n;
        m0 = sc.x * s0 * rc + sh.x;
        m1 = sc.y * s1 * rc + sh.y;
    }
    unsigned pk = (unsigned)f2bf(m0) | ((unsigned)f2bf(m1) << 16);
    xe_u[(size_t)e * 64 + l] = pk;
}

// ---------------------------------------------------------------------------
// Kernel G: per-vertex gather-reduce + ReLU.  One wave per vertex, no LDS.
// ---------------------------------------------------------------------------
__global__ __launch_bounds__(256) void k_vert_gather(
    const unsigned* __restrict__ xe_u, const unsigned* __restrict__ csrV,
    const int* __restrict__ voff, const int* __restrict__ vcnt,
    float* __restrict__ out) {
    const int v = blockIdx.x * 4 + (threadIdx.x >> 6);
    if (v >= N_V) return;
    const int l = threadIdx.x & 63;
    const int o = voff[v], n = vcnt[v];
    float s0 = 0.f, s1 = 0.f, s2 = 0.f, s3 = 0.f;
    int j = 0;
    for (; j + 3 < n; j += 4) {
        const int e0 = csrV[o + j],     e1 = csrV[o + j + 1];
        const int e2 = csrV[o + j + 2], e3 = csrV[o + j + 3];
        const unsigned u0 = xe_u[(size_t)e0 * 64 + l];
        const unsigned u1 = xe_u[(size_t)e1 * 64 + l];
        const unsigned u2 = xe_u[(size_t)e2 * 64 + l];
        const unsigned u3 = xe_u[(size_t)e3 * 64 + l];
        s0 += bf_lo(u0) + bf_lo(u1);
        s1 += bf_hi(u0) + bf_hi(u1);
        s2 += bf_lo(u2) + bf_lo(u3);
        s3 += bf_hi(u2) + bf_hi(u3);
    }
    for (; j < n; ++j) {
        const unsigned u0 = xe_u[(size_t)csrV[o + j] * 64 + l];
        s0 += bf_lo(u0);
        s1 += bf_hi(u0);
    }
    s0 += s2; s1 += s3;
    const float rc = 1.0f / (float)max(n, 1);
    ((float2*)out)[(size_t)v * 64 + l] =
        make_float2(fmaxf(s0 * rc, 0.f), fmaxf(s1 * rc, 0.f));
}

// ---------------------------------------------------------------------------
extern "C" void kernel_launch(void* const* d_in, const int* in_sizes, int n_in,
                              void* d_out, int out_size, void* d_ws, size_t ws_size,
                              hipStream_t stream) {
    const float* X     = (const float*)d_in[0];
    const int*   vid   = (const int*)d_in[1];
    const int*   eid   = (const int*)d_in[2];
    const float* W     = (const float*)d_in[3];
    const float* b     = (const float*)d_in[4];
    const float* gamma = (const float*)d_in[5];
    const float* beta  = (const float*)d_in[6];
    float* out = (float*)d_out;

    // workspace layout
    char* ws = (char*)d_ws;
    unsigned* h_u   = (unsigned*)ws;  ws += (size_t)N_V * 64 * 4;            // 25.6 MB
    unsigned* xe_u  = (unsigned*)ws;  ws += (size_t)N_E * 64 * 4;            //  5.1 MB
    unsigned* partE = (unsigned*)ws;  ws += (size_t)NB_E * EB_REGION * 4;    // 11.5 MB
    unsigned* partV = (unsigned*)ws;  ws += (size_t)NB_V * VB_REGION * 4;    // 12.8 MB
    unsigned* csrE  = (unsigned*)ws;  ws += (size_t)NB_E * EB_SORT * 4;      //  7.4 MB
    unsigned* csrV  = (unsigned*)ws;  ws += (size_t)NB_V * VB_SORT * 4;      //  7.2 MB
    int* eoff = (int*)ws;             ws += (size_t)N_E * 4;
    int* ecnt = (int*)ws;             ws += (size_t)N_E * 4;
    int* voff = (int*)ws;             ws += (size_t)N_V * 4;
    int* vcnt = (int*)ws;             ws += (size_t)N_V * 4;
    // --- zeroed region ---
    char* zbase = ws;
    int*   gcntE = (int*)ws;          ws += (size_t)NB_E * 4;
    int*   gcntV = (int*)ws;          ws += (size_t)NB_V * 4;
    float* sums  = (float*)ws;        ws += 256 * 4;
    // --- end zeroed region ---
    float* scale = (float*)ws;        ws += 128 * 4;
    float* shift = (float*)ws;        ws += 128 * 4;

    hipMemsetAsync(zbase, 0, (size_t)((char*)scale - zbase), stream);

    k_gemm_mfma<<<GEMM_BLOCKS, 256, 0, stream>>>(X, W, b, h_u);
    k_bn_stats<<<BN_BLOCKS, 256, 0, stream>>>(h_u, sums);
    k_bn_final<<<1, 128, 0, stream>>>(sums, gamma, beta, scale, shift);

    k_sort<NB_E, EB_SHIFT, 17, EB_REGION>
        <<<SORT_BLOCKS, 256, 0, stream>>>(eid, vid, gcntE, partE);
    k_sort<NB_V, VB_SHIFT, 15, VB_REGION>
        <<<SORT_BLOCKS, 256, 0, stream>>>(vid, eid, gcntV, partV);

    k_csr<64, 17, EB_SORT, EB_REGION, EB_SORT>
        <<<NB_E, 256, 0, stream>>>(partE, gcntE, N_E, eoff, ecnt, csrE);
    k_csr<256, 15, VB_SORT, VB_REGION, VB_SORT>
        <<<NB_V, 256, 0, stream>>>(partV, gcntV, N_V, voff, vcnt, csrV);

    k_edge_gather<<<(N_E + 3) / 4, 256, 0, stream>>>(h_u, csrE, eoff, ecnt,
                                                     scale, shift, xe_u);
    k_vert_gather<<<(N_V + 3) / 4, 256, 0, stream>>>(xe_u, csrV, voff, vcnt, out);
}

// Round 8
// 367.912 us; speedup vs baseline: 2.0250x; 1.0229x over previous
//
#include <hip/hip_runtime.h>
#include <hip/hip_bf16.h>

#define N_V 100000
#define N_E 20000
#define N_P 1600000
#define FDIM 128
#define HDIM 128
#define BN_EPS 1e-5f

// ---- bucket/sort geometry ----
#define SORT_C 4096
#define SORT_BLOCKS ((N_P + SORT_C - 1) / SORT_C)   // 391
#define NB_E 313                   // edge buckets (64 edges each)
#define EB_SHIFT 6
#define EB_REGION 9216             // slots per edge bucket region
#define EB_SORT 5888               // max valid entries per bucket (mean 5112)
#define NB_V 391                   // vertex buckets (256 vertices each)
#define VB_SHIFT 8
#define VB_REGION 8192
#define VB_SORT 4608               // max valid entries per bucket (mean 4096)
#define SENTINEL 0xFFFFFFFFu

typedef __attribute__((ext_vector_type(8))) short short8;
typedef __attribute__((ext_vector_type(4))) float floatx4;

__device__ __forceinline__ float bf_lo(unsigned u) {
    return __uint_as_float(u << 16);
}
__device__ __forceinline__ float bf_hi(unsigned u) {
    return __uint_as_float(u & 0xffff0000u);
}
// fp32 -> bf16 bits, round-to-nearest-even
__device__ __forceinline__ unsigned short f2bf(float f) {
    unsigned u = __float_as_uint(f);
    return (unsigned short)((u + 0x7fffu + ((u >> 16) & 1u)) >> 16);
}

// ---------------------------------------------------------------------------
// Kernel A: h = X @ W + b via bf16 MFMA, computed as C^T = W^T · X^T.
// ---------------------------------------------------------------------------
#define GEMM_BLOCKS 625
#define WT_STRIDE 136   // 128 + 8 bf16 pad -> 2-way-only LDS conflicts
__global__ __launch_bounds__(256) void k_gemm_mfma(
    const float* __restrict__ X, const float* __restrict__ W,
    const float* __restrict__ bias, unsigned* __restrict__ h_u) {
    __shared__ unsigned short WTs[FDIM * WT_STRIDE];   // ~34 KB
    const int t = threadIdx.x;
    for (int idx = t; idx < FDIM * HDIM; idx += 256) {
        const int k = idx >> 7, m = idx & 127;
        WTs[m * WT_STRIDE + k] = f2bf(W[idx]);
    }
    __syncthreads();

    const int wave = t >> 6, lane = t & 63;
    const int quad = lane >> 4, sub = lane & 15;
    const int nstrips = N_V / 16;  // 6250, exact

    for (int s = blockIdx.x * 4 + wave; s < nstrips; s += GEMM_BLOCKS * 4) {
        const int row0 = s * 16;
        short8 xf[4];
        const float* xp = X + (size_t)(row0 + sub) * FDIM + quad * 8;
        #pragma unroll
        for (int kt = 0; kt < 4; ++kt) {
            const float4 a = *(const float4*)(xp + kt * 32);
            const float4 b2 = *(const float4*)(xp + kt * 32 + 4);
            short8 f;
            f[0] = (short)f2bf(a.x);  f[1] = (short)f2bf(a.y);
            f[2] = (short)f2bf(a.z);  f[3] = (short)f2bf(a.w);
            f[4] = (short)f2bf(b2.x); f[5] = (short)f2bf(b2.y);
            f[6] = (short)f2bf(b2.z); f[7] = (short)f2bf(b2.w);
            xf[kt] = f;
        }
        #pragma unroll
        for (int tile = 0; tile < 8; ++tile) {
            floatx4 acc = {0.f, 0.f, 0.f, 0.f};
            const unsigned short* wp =
                WTs + (tile * 16 + sub) * WT_STRIDE + quad * 8;
            #pragma unroll
            for (int kt = 0; kt < 4; ++kt) {
                const short8 af = *(const short8*)(wp + kt * 32);
                acc = __builtin_amdgcn_mfma_f32_16x16x32_bf16(af, xf[kt], acc,
                                                              0, 0, 0);
            }
            const int ch = tile * 16 + quad * 4;
            const float4 bb = *(const float4*)(bias + ch);
            const float c0 = acc[0] + bb.x, c1 = acc[1] + bb.y;
            const float c2 = acc[2] + bb.z, c3 = acc[3] + bb.w;
            const unsigned lo = (unsigned)f2bf(c0) | ((unsigned)f2bf(c1) << 16);
            const unsigned hi = (unsigned)f2bf(c2) | ((unsigned)f2bf(c3) << 16);
            uint2* dst = (uint2*)(h_u + (size_t)(row0 + sub) * 64 + (ch >> 1));
            *dst = make_uint2(lo, hi);
        }
    }
}

// ---------------------------------------------------------------------------
// Kernel B: per-channel sum & sumsq of bf16 h
// ---------------------------------------------------------------------------
#define BN_BLOCKS 512
#define BN_ROWS_PER_BLOCK 196
__global__ __launch_bounds__(256) void k_bn_stats(
    const unsigned* __restrict__ h_u, float* __restrict__ sums /* [256] */) {
    const int t = threadIdx.x;
    const int c = t & 127, half = t >> 7;
    const int r0 = blockIdx.x * BN_ROWS_PER_BLOCK;
    const int r1 = min(r0 + BN_ROWS_PER_BLOCK, N_V);
    float s = 0.f, ss = 0.f;
    for (int r = r0 + half; r < r1; r += 2) {
        unsigned u = h_u[(size_t)r * 64 + (c >> 1)];
        float x = (c & 1) ? bf_hi(u) : bf_lo(u);
        s += x;
        ss += x * x;
    }
    __shared__ float ls[256], lss[256];
    ls[t] = s; lss[t] = ss;
    __syncthreads();
    if (t < 128) {
        atomicAdd(&sums[c],       ls[t] + ls[t + 128]);
        atomicAdd(&sums[128 + c], lss[t] + lss[t + 128]);
    }
}

// ---------------------------------------------------------------------------
// Kernel C: finalize BN -> scale/shift
// ---------------------------------------------------------------------------
__global__ void k_bn_final(const float* __restrict__ sums,
                           const float* __restrict__ gamma,
                           const float* __restrict__ beta,
                           float* __restrict__ scale, float* __restrict__ shift) {
    const int c = threadIdx.x;
    const float inv_n = 1.0f / (float)N_V;
    const float mu  = sums[c] * inv_n;
    const float var = sums[128 + c] * inv_n - mu * mu;
    const float inv = rsqrtf(var + BN_EPS);
    const float sc  = gamma[c] * inv;
    scale[c] = sc;
    shift[c] = beta[c] - mu * sc;
}

// ---------------------------------------------------------------------------
// Kernel D: dual-direction LDS-staged chunk sort, line-aligned full-line
// flush.  One pass over (eid, vid) builds BOTH partitions.
// ---------------------------------------------------------------------------
__global__ __launch_bounds__(256) void k_sort_dual(
    const int* __restrict__ vid, const int* __restrict__ eid,
    int* __restrict__ gcntE, int* __restrict__ gcntV,
    unsigned* __restrict__ partE, unsigned* __restrict__ partV) {
    __shared__ unsigned stageE[SORT_C];          // 16 KB
    __shared__ unsigned stageV[SORT_C];          // 16 KB
    __shared__ int histE[NB_E], curE[NB_E], offsE[NB_E], gbaseE[NB_E];
    __shared__ int histV[NB_V], curV[NB_V], offsV[NB_V], gbaseV[NB_V];
    __shared__ int partial[256];
    const int t = threadIdx.x;
    const int p0 = blockIdx.x * SORT_C;
    const int n = min(SORT_C, N_P - p0);

    for (int k = t; k < NB_E; k += 256) histE[k] = 0;
    for (int k = t; k < NB_V; k += 256) histV[k] = 0;
    __syncthreads();
    for (int i = t; i < n; i += 256) {
        atomicAdd(&histE[((unsigned)eid[p0 + i]) >> EB_SHIFT], 1);
        atomicAdd(&histV[((unsigned)vid[p0 + i]) >> VB_SHIFT], 1);
    }
    __syncthreads();
    // scan E
    {
        constexpr int G = (NB_E + 255) / 256;
        int loc[G]; int s = 0;
        #pragma unroll
        for (int g = 0; g < G; ++g) {
            int idx = t * G + g; loc[g] = s;
            if (idx < NB_E) s += histE[idx];
        }
        partial[t] = s;
        __syncthreads();
        for (int d = 1; d < 256; d <<= 1) {
            int x = (t >= d) ? partial[t - d] : 0;
            __syncthreads(); partial[t] += x; __syncthreads();
        }
        const int base = t ? partial[t - 1] : 0;
        #pragma unroll
        for (int g = 0; g < G; ++g) {
            int idx = t * G + g;
            if (idx < NB_E) { offsE[idx] = base + loc[g]; curE[idx] = base + loc[g]; }
        }
        __syncthreads();
    }
    // scan V
    {
        constexpr int G = (NB_V + 255) / 256;
        int loc[G]; int s = 0;
        #pragma unroll
        for (int g = 0; g < G; ++g) {
            int idx = t * G + g; loc[g] = s;
            if (idx < NB_V) s += histV[idx];
        }
        partial[t] = s;
        __syncthreads();
        for (int d = 1; d < 256; d <<= 1) {
            int x = (t >= d) ? partial[t - d] : 0;
            __syncthreads(); partial[t] += x; __syncthreads();
        }
        const int base = t ? partial[t - 1] : 0;
        #pragma unroll
        for (int g = 0; g < G; ++g) {
            int idx = t * G + g;
            if (idx < NB_V) { offsV[idx] = base + loc[g]; curV[idx] = base + loc[g]; }
        }
        __syncthreads();
    }
    // place both directions
    for (int i = t; i < n; i += 256) {
        const int ev = eid[p0 + i], vv = vid[p0 + i];
        const unsigned pkE = ((unsigned)(ev & 63) << 17) | (unsigned)vv;
        stageE[atomicAdd(&curE[(unsigned)ev >> EB_SHIFT], 1)] = pkE;
        const unsigned pkV = ((unsigned)(vv & 255) << 15) | (unsigned)ev;
        stageV[atomicAdd(&curV[(unsigned)vv >> VB_SHIFT], 1)] = pkV;
    }
    __syncthreads();
    // allocate line-aligned global space
    for (int k = t; k < NB_E; k += 256) {
        const int c = histE[k];
        gbaseE[k] = c ? atomicAdd(&gcntE[k], (c + 15) & ~15) : 0;
    }
    for (int k = t; k < NB_V; k += 256) {
        const int c = histV[k];
        gbaseV[k] = c ? atomicAdd(&gcntV[k], (c + 15) & ~15) : 0;
    }
    __syncthreads();
    // flush E
    for (int k = t >> 3; k < NB_E; k += 32) {
        const int c = histE[k];
        if (c == 0) continue;
        int cpad = (c + 15) & ~15;
        const int gb = gbaseE[k];
        if (gb >= EB_REGION) continue;
        cpad = min(cpad, EB_REGION - gb);
        unsigned* dst = partE + (size_t)k * EB_REGION + gb;
        const int lo = offsE[k];
        for (int j = t & 7; j < cpad; j += 8)
            dst[j] = (j < c) ? stageE[lo + j] : SENTINEL;
    }
    // flush V
    for (int k = t >> 3; k < NB_V; k += 32) {
        const int c = histV[k];
        if (c == 0) continue;
        int cpad = (c + 15) & ~15;
        const int gb = gbaseV[k];
        if (gb >= VB_REGION) continue;
        cpad = min(cpad, VB_REGION - gb);
        unsigned* dst = partV + (size_t)k * VB_REGION + gb;
        const int lo = offsV[k];
        for (int j = t & 7; j < cpad; j += 8)
            dst[j] = (j < c) ? stageV[lo + j] : SENTINEL;
    }
}

// ---------------------------------------------------------------------------
// Kernel E: bucket region -> compact sorted CSR (adjacency + seg off/cnt).
// ---------------------------------------------------------------------------
template <int NKEY, int PACK_SHIFT, int CAP, int REGION, int STRIDE>
__global__ __launch_bounds__(256) void k_csr(
    const unsigned* __restrict__ part, const int* __restrict__ gcnt,
    int nkeys_total, int* __restrict__ segoff, int* __restrict__ segcnt,
    unsigned* __restrict__ csr) {
    __shared__ unsigned A[CAP];
    __shared__ unsigned B[CAP];
    __shared__ int hist[NKEY], offs[NKEY + 1], cur[NKEY];
    __shared__ int lcur;
    const int bkt = blockIdx.x;
    const int t = threadIdx.x;
    const int lane = t & 63;
    const unsigned mask = (1u << PACK_SHIFT) - 1u;
    const int tot = min(gcnt[bkt], REGION);
    const unsigned* src = part + (size_t)bkt * REGION;

    if (t == 0) lcur = 0;
    for (int k = t; k < NKEY; k += 256) hist[k] = 0;
    __syncthreads();
    for (int i = t; i < ((tot + 255) & ~255); i += 256) {
        unsigned a = (i < tot) ? src[i] : SENTINEL;
        const bool valid = (a != SENTINEL);
        const unsigned long long bal = __ballot(valid);
        int wbase = 0;
        if (lane == 0) wbase = atomicAdd(&lcur, __popcll(bal));
        wbase = __shfl(wbase, 0);
        if (valid) {
            const int pos = wbase + __popcll(bal & ((1ull << lane) - 1ull));
            if (pos < CAP) A[pos] = a;
        }
    }
    __syncthreads();
    const int total = min(lcur, CAP);
    for (int i = t; i < total; i += 256)
        atomicAdd(&hist[A[i] >> PACK_SHIFT], 1);
    __syncthreads();
    if (t == 0) {
        int acc = 0;
        for (int k = 0; k < NKEY; ++k) { offs[k] = acc; acc += hist[k]; }
        offs[NKEY] = acc;
    }
    for (int k = t; k < NKEY; k += 256) cur[k] = 0;
    __syncthreads();
    for (int i = t; i < total; i += 256) {
        const unsigned a = A[i];
        const int k = a >> PACK_SHIFT;
        const int pos = offs[k] + atomicAdd(&cur[k], 1);
        B[pos] = a & mask;
    }
    __syncthreads();
    unsigned* dst = csr + (size_t)bkt * STRIDE;
    for (int i = t; i < total; i += 256) dst[i] = B[i];
    for (int k = t; k < NKEY; k += 256) {
        const int g = bkt * NKEY + k;
        if (g < nkeys_total) {
            segoff[g] = bkt * STRIDE + offs[k];
            segcnt[g] = hist[k];
        }
    }
}

// ---------------------------------------------------------------------------
// Kernel F: per-edge gather-reduce.  One wave per edge; split-wave uint2
// loads (lanes 0-31 row j, 32-63 row j+1; 4 channels/lane), 8-wide MLP.
// ---------------------------------------------------------------------------
__global__ __launch_bounds__(256) void k_edge_gather(
    const unsigned* __restrict__ h_u, const unsigned* __restrict__ csrE,
    const int* __restrict__ eoff, const int* __restrict__ ecnt,
    const float* __restrict__ scale, const float* __restrict__ shift,
    unsigned* __restrict__ xe_u) {
    const int e = blockIdx.x * 4 + (threadIdx.x >> 6);
    if (e >= N_E) return;
    const int l = threadIdx.x & 63;
    const int half = l >> 5, sl = l & 31;
    const int o = eoff[e], n = ecnt[e];
    float s0 = 0.f, s1 = 0.f, s2 = 0.f, s3 = 0.f;
    int j = 0;
    for (; j + 7 < n; j += 8) {
        const int r0 = csrE[o + j + half];
        const int r1 = csrE[o + j + 2 + half];
        const int r2 = csrE[o + j + 4 + half];
        const int r3 = csrE[o + j + 6 + half];
        const uint2 u0 = *(const uint2*)(h_u + (size_t)r0 * 64 + 2 * sl);
        const uint2 u1 = *(const uint2*)(h_u + (size_t)r1 * 64 + 2 * sl);
        const uint2 u2 = *(const uint2*)(h_u + (size_t)r2 * 64 + 2 * sl);
        const uint2 u3 = *(const uint2*)(h_u + (size_t)r3 * 64 + 2 * sl);
        s0 += bf_lo(u0.x) + bf_lo(u1.x) + bf_lo(u2.x) + bf_lo(u3.x);
        s1 += bf_hi(u0.x) + bf_hi(u1.x) + bf_hi(u2.x) + bf_hi(u3.x);
        s2 += bf_lo(u0.y) + bf_lo(u1.y) + bf_lo(u2.y) + bf_lo(u3.y);
        s3 += bf_hi(u0.y) + bf_hi(u1.y) + bf_hi(u2.y) + bf_hi(u3.y);
    }
    for (; j < n; j += 2) {
        if (j + half < n) {
            const int r = csrE[o + j + half];
            const uint2 u = *(const uint2*)(h_u + (size_t)r * 64 + 2 * sl);
            s0 += bf_lo(u.x); s1 += bf_hi(u.x);
            s2 += bf_lo(u.y); s3 += bf_hi(u.y);
        }
    }
    s0 += __shfl_xor(s0, 32); s1 += __shfl_xor(s1, 32);
    s2 += __shfl_xor(s2, 32); s3 += __shfl_xor(s3, 32);
    if (half == 0) {
        float m0 = 0.f, m1 = 0.f, m2 = 0.f, m3 = 0.f;
        if (n > 0) {
            const float rc = 1.0f / (float)n;
            const float4 sc = ((const float4*)scale)[sl];
            const float4 sh = ((const float4*)shift)[sl];
            m0 = sc.x * s0 * rc + sh.x;
            m1 = sc.y * s1 * rc + sh.y;
            m2 = sc.z * s2 * rc + sh.z;
            m3 = sc.w * s3 * rc + sh.w;
        }
        uint2 pk;
        pk.x = (unsigned)f2bf(m0) | ((unsigned)f2bf(m1) << 16);
        pk.y = (unsigned)f2bf(m2) | ((unsigned)f2bf(m3) << 16);
        *(uint2*)(xe_u + (size_t)e * 64 + 2 * sl) = pk;
    }
}

// ---------------------------------------------------------------------------
// Kernel G: per-vertex gather-reduce + ReLU.  Split-wave uint2, 4-wide MLP.
// ---------------------------------------------------------------------------
__global__ __launch_bounds__(256) void k_vert_gather(
    const unsigned* __restrict__ xe_u, const unsigned* __restrict__ csrV,
    const int* __restrict__ voff, const int* __restrict__ vcnt,
    float* __restrict__ out) {
    const int v = blockIdx.x * 4 + (threadIdx.x >> 6);
    if (v >= N_V) return;
    const int l = threadIdx.x & 63;
    const int half = l >> 5, sl = l & 31;
    const int o = voff[v], n = vcnt[v];
    float s0 = 0.f, s1 = 0.f, s2 = 0.f, s3 = 0.f;
    int j = 0;
    for (; j + 3 < n; j += 4) {
        const int r0 = csrV[o + j + half];
        const int r1 = csrV[o + j + 2 + half];
        const uint2 u0 = *(const uint2*)(xe_u + (size_t)r0 * 64 + 2 * sl);
        const uint2 u1 = *(const uint2*)(xe_u + (size_t)r1 * 64 + 2 * sl);
        s0 += bf_lo(u0.x) + bf_lo(u1.x);
        s1 += bf_hi(u0.x) + bf_hi(u1.x);
        s2 += bf_lo(u0.y) + bf_lo(u1.y);
        s3 += bf_hi(u0.y) + bf_hi(u1.y);
    }
    for (; j < n; j += 2) {
        if (j + half < n) {
            const int r = csrV[o + j + half];
            const uint2 u = *(const uint2*)(xe_u + (size_t)r * 64 + 2 * sl);
            s0 += bf_lo(u.x); s1 += bf_hi(u.x);
            s2 += bf_lo(u.y); s3 += bf_hi(u.y);
        }
    }
    s0 += __shfl_xor(s0, 32); s1 += __shfl_xor(s1, 32);
    s2 += __shfl_xor(s2, 32); s3 += __shfl_xor(s3, 32);
    if (half == 0) {
        const float rc = 1.0f / (float)max(n, 1);
        float4 r;
        r.x = fmaxf(s0 * rc, 0.f);
        r.y = fmaxf(s1 * rc, 0.f);
        r.z = fmaxf(s2 * rc, 0.f);
        r.w = fmaxf(s3 * rc, 0.f);
        ((float4*)out)[(size_t)v * 32 + sl] = r;
    }
}

// ---------------------------------------------------------------------------
extern "C" void kernel_launch(void* const* d_in, const int* in_sizes, int n_in,
                              void* d_out, int out_size, void* d_ws, size_t ws_size,
                              hipStream_t stream) {
    const float* X     = (const float*)d_in[0];
    const int*   vid   = (const int*)d_in[1];
    const int*   eid   = (const int*)d_in[2];
    const float* W     = (const float*)d_in[3];
    const float* b     = (const float*)d_in[4];
    const float* gamma = (const float*)d_in[5];
    const float* beta  = (const float*)d_in[6];
    float* out = (float*)d_out;

    // workspace layout
    char* ws = (char*)d_ws;
    unsigned* h_u   = (unsigned*)ws;  ws += (size_t)N_V * 64 * 4;            // 25.6 MB
    unsigned* xe_u  = (unsigned*)ws;  ws += (size_t)N_E * 64 * 4;            //  5.1 MB
    unsigned* partE = (unsigned*)ws;  ws += (size_t)NB_E * EB_REGION * 4;    // 11.5 MB
    unsigned* partV = (unsigned*)ws;  ws += (size_t)NB_V * VB_REGION * 4;    // 12.8 MB
    unsigned* csrE  = (unsigned*)ws;  ws += (size_t)NB_E * EB_SORT * 4;      //  7.4 MB
    unsigned* csrV  = (unsigned*)ws;  ws += (size_t)NB_V * VB_SORT * 4;      //  7.2 MB
    int* eoff = (int*)ws;             ws += (size_t)N_E * 4;
    int* ecnt = (int*)ws;             ws += (size_t)N_E * 4;
    int* voff = (int*)ws;             ws += (size_t)N_V * 4;
    int* vcnt = (int*)ws;             ws += (size_t)N_V * 4;
    // --- zeroed region ---
    char* zbase = ws;
    int*   gcntE = (int*)ws;          ws += (size_t)NB_E * 4;
    int*   gcntV = (int*)ws;          ws += (size_t)NB_V * 4;
    float* sums  = (float*)ws;        ws += 256 * 4;
    // --- end zeroed region ---
    float* scale = (float*)ws;        ws += 128 * 4;
    float* shift = (float*)ws;        ws += 128 * 4;

    hipMemsetAsync(zbase, 0, (size_t)((char*)scale - zbase), stream);

    k_gemm_mfma<<<GEMM_BLOCKS, 256, 0, stream>>>(X, W, b, h_u);
    k_bn_stats<<<BN_BLOCKS, 256, 0, stream>>>(h_u, sums);
    k_bn_final<<<1, 128, 0, stream>>>(sums, gamma, beta, scale, shift);

    k_sort_dual<<<SORT_BLOCKS, 256, 0, stream>>>(vid, eid, gcntE, gcntV,
                                                 partE, partV);

    k_csr<64, 17, EB_SORT, EB_REGION, EB_SORT>
        <<<NB_E, 256, 0, stream>>>(partE, gcntE, N_E, eoff, ecnt, csrE);
    k_csr<256, 15, VB_SORT, VB_REGION, VB_SORT>
        <<<NB_V, 256, 0, stream>>>(partV, gcntV, N_V, voff, vcnt, csrV);

    k_edge_gather<<<(N_E + 3) / 4, 256, 0, stream>>>(h_u, csrE, eoff, ecnt,
                                                     scale, shift, xe_u);
    k_vert_gather<<<(N_V + 3) / 4, 256, 0, stream>>>(xe_u, csrV, voff, vcnt, out);
}